// Round 1
// baseline (530.284 us; speedup 1.0000x reference)
//
#include <hip/hip_runtime.h>
#include <hip/hip_bf16.h>

// QKVAttention: L2-distance attention. B=8, T=4096, C=192, fp32 in/out.
// out[b,t,:] = sum_s exp(-||q_t-k_s||*192^-0.5) v_s / sum_s exp(...)
// exp arg is bounded in [-3,0] -> NO online softmax needed.
//
// Pipeline:
//   1) convert_kernel : q,k -> bf16 (d_ws), per-token raw sumsq (from ROUNDED
//      values so diagonal d2 is exactly 0 under the bf16 MFMA dot).
//   2) transpose_v    : v -> bf16 vt[b][c][s] so PV B-fragments are contiguous.
//   3) attn_main      : barrier-free fused kernel. Fragments loaded straight
//      from global (L2-resident per-batch via blockIdx%8 == XCD swizzle).
//      LDS only for the wave-private P C-layout->A-layout round trip.
// d_ws usage: 3*8*4096*192*2 B (qb,kb,vt) + 2*8*4096*4 B (q2,k2) ~ 38 MB.

#define BB 8
#define TT 4096
#define CD 192

typedef __attribute__((ext_vector_type(8))) short short8;   // 8 bf16 (4 VGPR)
typedef __attribute__((ext_vector_type(4))) float float4v;  // MFMA C/D

// (log2 e)^2 / 192  : p = exp2(-sqrt(A2C * max(d2_raw,0)))
constexpr float A2C = (float)(2.0813689810056077 / 192.0);

static __device__ __forceinline__ unsigned short f2bf(float f) {
  unsigned u = __builtin_bit_cast(unsigned, f);
  unsigned r = u + 0x7fffu + ((u >> 16) & 1u);   // RNE (inputs are finite)
  return (unsigned short)(r >> 16);
}
static __device__ __forceinline__ float bf2f(unsigned short b) {
  return __builtin_bit_cast(float, (unsigned)b << 16);
}

// ---------------- prepass 1: q,k -> bf16 + raw row sumsq --------------------
__global__ __launch_bounds__(256) void convert_kernel(
    const float* __restrict__ qkv, unsigned short* __restrict__ qb,
    unsigned short* __restrict__ kb, float* __restrict__ q2,
    float* __restrict__ k2) {
  int tok = blockIdx.x * 4 + (threadIdx.x >> 6);
  int lane = threadIdx.x & 63;
  const float* row = qkv + (size_t)tok * (3 * CD);
  float q2s = 0.f, k2s = 0.f;
#pragma unroll
  for (int i = 0; i < 3; ++i) {
    int c = lane + 64 * i;
    unsigned short hb = f2bf(row[c]);
    qb[(size_t)tok * CD + c] = hb;
    float fr = bf2f(hb);
    q2s += fr * fr;
  }
#pragma unroll
  for (int i = 0; i < 3; ++i) {
    int c = lane + 64 * i;
    unsigned short hb = f2bf(row[CD + c]);
    kb[(size_t)tok * CD + c] = hb;
    float fr = bf2f(hb);
    k2s += fr * fr;
  }
#pragma unroll
  for (int m = 1; m < 64; m <<= 1) {
    q2s += __shfl_xor(q2s, m);
    k2s += __shfl_xor(k2s, m);
  }
  if (lane == 0) { q2[tok] = q2s; k2[tok] = k2s; }
}

// ---------------- prepass 2: v -> bf16, transposed vt[b][c][s] --------------
__global__ __launch_bounds__(256) void transpose_v(
    const float* __restrict__ qkv, unsigned short* __restrict__ vt) {
  __shared__ float tile[64][65];
  int bid = blockIdx.x;           // 8 * 64 * 3 = 1536
  int b = bid / 192;
  int r = bid % 192;
  int s0 = (r / 3) * 64, c0 = (r % 3) * 64;
  for (int i = threadIdx.x; i < 64 * 64; i += 256) {
    int sl = i >> 6, cl = i & 63;
    tile[sl][cl] = qkv[(size_t)(b * TT + s0 + sl) * (3 * CD) + 2 * CD + c0 + cl];
  }
  __syncthreads();
  for (int i = threadIdx.x; i < 64 * 64; i += 256) {
    int cl = i >> 6, sl = i & 63;   // lanes -> sl consecutive: coalesced store
    vt[(size_t)(b * CD + c0 + cl) * TT + s0 + sl] = f2bf(tile[sl][cl]);
  }
}

// ---------------- main fused attention --------------------------------------
// grid 1024 = 8 b * 128 qtiles (32 rows). block 128 = 2 waves, split-K:
// wave w covers s in [w*2048,(w+1)*2048). 4 blocks/CU, 8 waves/CU.
__global__ __launch_bounds__(128, 2) void attn_main(
    const unsigned short* __restrict__ qb, const unsigned short* __restrict__ kb,
    const unsigned short* __restrict__ vt, const float* __restrict__ q2,
    const float* __restrict__ k2, float* __restrict__ out) {
  // smem: P scratch 2 waves * [32][68] fp32 = 4352 fl; epilogue combine 64*104.
  __shared__ float smem[6656];

  const int tid = threadIdx.x;
  const int w = tid >> 6;
  const int lane = tid & 63;
  const int L = lane & 15;       // MFMA "lane&15" index
  const int q = lane >> 4;       // quad
  const int b = blockIdx.x & 7;  // XCD swizzle: batch b -> XCD b
  const int qt = blockIdx.x >> 3;
  const int q0 = qt * 32;
  const size_t bT = (size_t)b * TT;

  // Q fragments (A-layout: A[m=L][k=q*8+j], chunks of 32 over C=192)
  short8 qf[2][6];
#pragma unroll
  for (int mt = 0; mt < 2; ++mt)
#pragma unroll
    for (int ch = 0; ch < 6; ++ch)
      qf[mt][ch] = *(const short8*)(qb + (bT + q0 + mt * 16 + L) * CD + ch * 32 + q * 8);

  float q2l[2][4];
#pragma unroll
  for (int mt = 0; mt < 2; ++mt)
#pragma unroll
    for (int r = 0; r < 4; ++r)
      q2l[mt][r] = q2[bT + q0 + mt * 16 + 4 * q + r];

  float4v oacc[2][12];
#pragma unroll
  for (int mt = 0; mt < 2; ++mt)
#pragma unroll
    for (int nt = 0; nt < 12; ++nt) oacc[mt][nt] = (float4v){0.f, 0.f, 0.f, 0.f};
  float lsum[2][4] = {{0.f, 0.f, 0.f, 0.f}, {0.f, 0.f, 0.f, 0.f}};

  const int pbase = w * 2176;  // 32*68 floats per wave

#pragma unroll 1
  for (int it = 0; it < 32; ++it) {
    const int s0a = w * 2048 + it * 64;

    float k2l[4];
#pragma unroll
    for (int nt = 0; nt < 4; ++nt) k2l[nt] = k2[bT + s0a + nt * 16 + L];

    // ---- S = Q.K^T (raw bf16 dots, fp32 acc) ----
    float4v sacc[2][4];
#pragma unroll
    for (int mt = 0; mt < 2; ++mt)
#pragma unroll
      for (int nt = 0; nt < 4; ++nt) sacc[mt][nt] = (float4v){0.f, 0.f, 0.f, 0.f};
#pragma unroll
    for (int ch = 0; ch < 6; ++ch) {
#pragma unroll
      for (int nt = 0; nt < 4; ++nt) {
        short8 kf = *(const short8*)(kb + (bT + s0a + nt * 16 + L) * CD + ch * 32 + q * 8);
        sacc[0][nt] = __builtin_amdgcn_mfma_f32_16x16x32_bf16(qf[0][ch], kf, sacc[0][nt], 0, 0, 0);
        sacc[1][nt] = __builtin_amdgcn_mfma_f32_16x16x32_bf16(qf[1][ch], kf, sacc[1][nt], 0, 0, 0);
      }
    }

    // ---- P = exp(-dist); C-layout: row = 4q+r, col = nt*16+L ----
#pragma unroll
    for (int mt = 0; mt < 2; ++mt)
#pragma unroll
      for (int nt = 0; nt < 4; ++nt)
#pragma unroll
        for (int r = 0; r < 4; ++r) {
          float dot = sacc[mt][nt][r];
          float t = fmaf(-2.f, dot, q2l[mt][r] + k2l[nt]);  // raw d2
          float y = fmaxf(t, 0.f) * A2C;
          float p = __builtin_amdgcn_exp2f(-__builtin_amdgcn_sqrtf(y));
          lsum[mt][r] += p;
          smem[pbase + (mt * 16 + 4 * q + r) * 68 + nt * 16 + L] = p;
        }

    // ---- O += P.V  (P via LDS round-trip to A-layout; V from global vt) ----
#pragma unroll
    for (int ch2 = 0; ch2 < 2; ++ch2) {
      short8 paf[2];
#pragma unroll
      for (int mt = 0; mt < 2; ++mt) {
        const float* ps = &smem[pbase + (mt * 16 + L) * 68 + ch2 * 32 + q * 8];
        float4v p0 = *(const float4v*)ps;
        float4v p1 = *(const float4v*)(ps + 4);
        short8 pa;
#pragma unroll
        for (int j = 0; j < 4; ++j) {
          pa[j] = (short)f2bf(p0[j]);
          pa[j + 4] = (short)f2bf(p1[j]);
        }
        paf[mt] = pa;
      }
#pragma unroll
      for (int nt = 0; nt < 12; ++nt) {
        short8 vf = *(const short8*)(vt + ((size_t)b * CD + nt * 16 + L) * TT + s0a + ch2 * 32 + q * 8);
        oacc[0][nt] = __builtin_amdgcn_mfma_f32_16x16x32_bf16(paf[0], vf, oacc[0][nt], 0, 0, 0);
        oacc[1][nt] = __builtin_amdgcn_mfma_f32_16x16x32_bf16(paf[1], vf, oacc[1][nt], 0, 0, 0);
      }
    }
  }

  // ---- row-sum reduce across the 16 columns held in the quad's lanes ----
#pragma unroll
  for (int mt = 0; mt < 2; ++mt)
#pragma unroll
    for (int r = 0; r < 4; ++r) {
#pragma unroll
      for (int m = 1; m < 16; m <<= 1) lsum[mt][r] += __shfl_xor(lsum[mt][r], m);
    }

  // ---- split-K combine (wave1 -> LDS, wave0 adds + writes out) ----
  __syncthreads();
  if (w == 1) {
#pragma unroll
    for (int mt = 0; mt < 2; ++mt) {
#pragma unroll
      for (int nt = 0; nt < 12; ++nt)
#pragma unroll
        for (int r = 0; r < 4; ++r)
          smem[lane * 104 + (mt * 12 + nt) * 4 + r] = oacc[mt][nt][r];
#pragma unroll
      for (int r = 0; r < 4; ++r) smem[lane * 104 + 96 + mt * 4 + r] = lsum[mt][r];
    }
  }
  __syncthreads();
  if (w == 0) {
#pragma unroll
    for (int mt = 0; mt < 2; ++mt) {
      float linv[4];
#pragma unroll
      for (int r = 0; r < 4; ++r)
        linv[r] = 1.f / (lsum[mt][r] + smem[lane * 104 + 96 + mt * 4 + r]);
#pragma unroll
      for (int nt = 0; nt < 12; ++nt)
#pragma unroll
        for (int r = 0; r < 4; ++r) {
          float v = (oacc[mt][nt][r] + smem[lane * 104 + (mt * 12 + nt) * 4 + r]) * linv[r];
          out[((size_t)b * TT + q0 + mt * 16 + 4 * q + r) * CD + nt * 16 + L] = v;
        }
    }
  }
}

extern "C" void kernel_launch(void* const* d_in, const int* in_sizes, int n_in,
                              void* d_out, int out_size, void* d_ws, size_t ws_size,
                              hipStream_t stream) {
  (void)in_sizes; (void)n_in; (void)out_size; (void)ws_size;
  const float* qkv = (const float*)d_in[0];
  float* out = (float*)d_out;

  unsigned short* qb = (unsigned short*)d_ws;
  unsigned short* kb = qb + (size_t)BB * TT * CD;
  unsigned short* vt = kb + (size_t)BB * TT * CD;
  float* q2 = (float*)(vt + (size_t)BB * TT * CD);
  float* k2 = q2 + (size_t)BB * TT;

  convert_kernel<<<BB * TT / 4, 256, 0, stream>>>(qkv, qb, kb, q2, k2);
  transpose_v<<<BB * 64 * 3, 256, 0, stream>>>(qkv, vt);
  attn_main<<<BB * (TT / 32), 128, 0, stream>>>(qb, kb, vt, q2, k2, out);
}

// Round 2
// 487.099 us; speedup vs baseline: 1.0887x; 1.0887x over previous
//
#include <hip/hip_runtime.h>
#include <hip/hip_bf16.h>

// QKVAttention: L2-distance attention. B=8, T=4096, C=192, fp32 in/out.
// out[b,t,:] = sum_s exp(-||q_t-k_s||*192^-0.5) v_s / sum_s exp(...)
// exp arg bounded in [-3,0] -> no online softmax needed.
//
// R2 change: Q/K/V pre-swizzled into MFMA-fragment-contiguous layout.
// Unit = (16 tokens x 32 channels) stored as 64 lanes x 16B (short8) = 1KB,
// lane (q=lane>>4, L=lane&15) holds tok s16*16+L, channels ch*32+q*8..+7.
// Main-kernel fragment loads are then single coalesced 1KB transactions
// (was: 16 scattered 64B segments -> L2 request-path bound at 7.4 TB/s eff).
//
// ws: qsw,ksw,vsw 12.6MB each + q2,k2 (fp32, atomically accumulated).

#define BB 8
#define TT 4096
#define CD 192

typedef __attribute__((ext_vector_type(8))) short short8;   // 8 bf16 (4 VGPR)
typedef __attribute__((ext_vector_type(4))) float float4v;  // MFMA C/D

// (log2 e)^2 / 192  : p = exp2(-sqrt(A2C * max(d2_raw,0)))
constexpr float A2C = (float)(2.0813689810056077 / 192.0);

static __device__ __forceinline__ unsigned short f2bf(float f) {
  unsigned u = __builtin_bit_cast(unsigned, f);
  unsigned r = u + 0x7fffu + ((u >> 16) & 1u);   // RNE (inputs finite)
  return (unsigned short)(r >> 16);
}
static __device__ __forceinline__ float bf2f(unsigned short b) {
  return __builtin_bit_cast(float, (unsigned)b << 16);
}

// ---------------- prepass 1: q,k -> fragment-swizzled bf16 + row sumsq ------
// wave unit id = ((b*256 + s16)*6 + ch)*2 + which (which: 0=q 1=k)
// lane (q,L): reads qkv[b][s16*16+L][which*192 + ch*32+q*8 .. +7] (2x float4,
// wave = 16 full 128B lines), stores one short8 coalesced, quad-reduces
// rounded sumsq and atomicAdds into q2/k2 (pre-zeroed via hipMemsetAsync).
__global__ __launch_bounds__(256) void swizzle_qk(
    const float* __restrict__ qkv, short8* __restrict__ qsw,
    short8* __restrict__ ksw, float* __restrict__ q2,
    float* __restrict__ k2) {
  int id = blockIdx.x * 4 + (threadIdx.x >> 6);   // wave unit
  int lane = threadIdx.x & 63;
  int L = lane & 15, q = lane >> 4;
  int which = id & 1;
  int u = id >> 1;                 // (b*256+s16)*6 + ch
  int ch = u % 6;
  int bs16 = u / 6;                // b*256 + s16
  int b = bs16 >> 8;
  int s16 = bs16 & 255;

  const float* src = qkv + ((size_t)(b * TT + s16 * 16 + L)) * (3 * CD)
                         + which * CD + ch * 32 + q * 8;
  float4v x0 = *(const float4v*)src;
  float4v x1 = *(const float4v*)(src + 4);

  short8 frag;
  float ss = 0.f;
#pragma unroll
  for (int j = 0; j < 4; ++j) {
    unsigned short h0 = f2bf(x0[j]), h1 = f2bf(x1[j]);
    frag[j] = (short)h0;
    frag[j + 4] = (short)h1;
    float f0 = bf2f(h0), f1 = bf2f(h1);
    ss += f0 * f0 + f1 * f1;
  }
  (which ? ksw : qsw)[(size_t)u * 64 + lane] = frag;

  ss += __shfl_xor(ss, 16);
  ss += __shfl_xor(ss, 32);        // lanes 0..15 hold sum over 4 quads
  if (lane < 16)
    atomicAdd((which ? k2 : q2) + b * TT + s16 * 16 + lane, ss);
}

// ---------------- prepass 2: v -> fragment-swizzled bf16 (transposed) -------
// block = (b, sc): 32 tokens. LDS-stage v[32][192] fp32 (coalesced float4
// reads), then emit 12 nt2-units x 64 lanes: lane (q,L) holds
// v[sc*32+q*8+j][nt2*16+L], j=0..7. Stores coalesced 16B.
__global__ __launch_bounds__(256) void swizzle_v(
    const float* __restrict__ qkv, short8* __restrict__ vsw) {
  __shared__ float tile[32 * CD];
  int t = threadIdx.x;
  int b = blockIdx.x >> 7;
  int sc = blockIdx.x & 127;
#pragma unroll
  for (int i = 0; i < 6; ++i) {
    int fi = (i * 256 + t) * 4;
    int row = fi / CD, col = fi % CD;
    *(float4v*)&tile[fi] =
        *(const float4v*)(qkv + ((size_t)(b * TT + sc * 32 + row)) * (3 * CD)
                          + 2 * CD + col);
  }
  __syncthreads();
#pragma unroll
  for (int uu = 0; uu < 3; ++uu) {
    int u = uu * 256 + t;
    int lane = u & 63, nt2 = u >> 6;
    int L = lane & 15, q = lane >> 4;
    short8 frag;
#pragma unroll
    for (int j = 0; j < 8; ++j)
      frag[j] = (short)f2bf(tile[(q * 8 + j) * CD + nt2 * 16 + L]);
    vsw[((size_t)(b * 12 + nt2) * 128 + sc) * 64 + lane] = frag;
  }
}

// ---------------- main fused attention --------------------------------------
// grid 1024 = 8 b * 128 qtiles (32 rows). block 128 = 2 waves, split-K:
// wave w covers s in [w*2048,(w+1)*2048). 4 blocks/CU, 8 waves/CU.
__global__ __launch_bounds__(128, 2) void attn_main(
    const short8* __restrict__ qsw, const short8* __restrict__ ksw,
    const short8* __restrict__ vsw, const float* __restrict__ q2,
    const float* __restrict__ k2, float* __restrict__ out) {
  // smem: P scratch 2 waves * [32][68] fp32 = 4352 fl; epilogue combine 64*104.
  __shared__ float smem[6656];

  const int tid = threadIdx.x;
  const int w = tid >> 6;
  const int lane = tid & 63;
  const int L = lane & 15;       // MFMA "lane&15" index
  const int q = lane >> 4;       // quad
  const int b = blockIdx.x & 7;  // XCD swizzle: batch b -> XCD b
  const int qt = blockIdx.x >> 3;
  const int q0 = qt * 32;
  const size_t bT = (size_t)b * TT;

  // Q fragments from swizzled layout: unit ((b*256 + s16)*6 + ch), coalesced.
  short8 qf[2][6];
#pragma unroll
  for (int mt = 0; mt < 2; ++mt)
#pragma unroll
    for (int ch = 0; ch < 6; ++ch)
      qf[mt][ch] = qsw[((size_t)(b * 256 + (q0 >> 4) + mt) * 6 + ch) * 64 + lane];

  float q2l[2][4];
#pragma unroll
  for (int mt = 0; mt < 2; ++mt)
#pragma unroll
    for (int r = 0; r < 4; ++r)
      q2l[mt][r] = q2[bT + q0 + mt * 16 + 4 * q + r];

  float4v oacc[2][12];
#pragma unroll
  for (int mt = 0; mt < 2; ++mt)
#pragma unroll
    for (int nt = 0; nt < 12; ++nt) oacc[mt][nt] = (float4v){0.f, 0.f, 0.f, 0.f};
  float lsum[2][4] = {{0.f, 0.f, 0.f, 0.f}, {0.f, 0.f, 0.f, 0.f}};

  const int pbase = w * 2176;  // 32*68 floats per wave

#pragma unroll 1
  for (int it = 0; it < 32; ++it) {
    const int s0a = w * 2048 + it * 64;
    const int s16b = s0a >> 4;   // base s16 group
    const int scb = s0a >> 5;    // base s32 chunk

    float k2l[4];
#pragma unroll
    for (int nt = 0; nt < 4; ++nt) k2l[nt] = k2[bT + s0a + nt * 16 + L];

    // ---- S = Q.K^T (raw bf16 dots, fp32 acc); kf loads coalesced 1KB ----
    float4v sacc[2][4];
#pragma unroll
    for (int mt = 0; mt < 2; ++mt)
#pragma unroll
      for (int nt = 0; nt < 4; ++nt) sacc[mt][nt] = (float4v){0.f, 0.f, 0.f, 0.f};
#pragma unroll
    for (int ch = 0; ch < 6; ++ch) {
#pragma unroll
      for (int nt = 0; nt < 4; ++nt) {
        short8 kf = ksw[((size_t)(b * 256 + s16b + nt) * 6 + ch) * 64 + lane];
        sacc[0][nt] = __builtin_amdgcn_mfma_f32_16x16x32_bf16(qf[0][ch], kf, sacc[0][nt], 0, 0, 0);
        sacc[1][nt] = __builtin_amdgcn_mfma_f32_16x16x32_bf16(qf[1][ch], kf, sacc[1][nt], 0, 0, 0);
      }
    }

    // ---- P = exp(-dist); C-layout: row = 4q+r, col = nt*16+L ----
#pragma unroll
    for (int mt = 0; mt < 2; ++mt)
#pragma unroll
      for (int nt = 0; nt < 4; ++nt)
#pragma unroll
        for (int r = 0; r < 4; ++r) {
          float dot = sacc[mt][nt][r];
          float t = fmaf(-2.f, dot, q2l[mt][r] + k2l[nt]);  // raw d2
          float y = fmaxf(t, 0.f) * A2C;
          float p = __builtin_amdgcn_exp2f(-__builtin_amdgcn_sqrtf(y));
          lsum[mt][r] += p;
          smem[pbase + (mt * 16 + 4 * q + r) * 68 + nt * 16 + L] = p;
        }

    // ---- O += P.V  (P via LDS round-trip to A-layout; vf coalesced 1KB) ----
#pragma unroll
    for (int ch2 = 0; ch2 < 2; ++ch2) {
      short8 paf[2];
#pragma unroll
      for (int mt = 0; mt < 2; ++mt) {
        const float* ps = &smem[pbase + (mt * 16 + L) * 68 + ch2 * 32 + q * 8];
        float4v p0 = *(const float4v*)ps;
        float4v p1 = *(const float4v*)(ps + 4);
        short8 pa;
#pragma unroll
        for (int j = 0; j < 4; ++j) {
          pa[j] = (short)f2bf(p0[j]);
          pa[j + 4] = (short)f2bf(p1[j]);
        }
        paf[mt] = pa;
      }
#pragma unroll
      for (int nt = 0; nt < 12; ++nt) {
        short8 vf = vsw[((size_t)(b * 12 + nt) * 128 + scb + ch2) * 64 + lane];
        oacc[0][nt] = __builtin_amdgcn_mfma_f32_16x16x32_bf16(paf[0], vf, oacc[0][nt], 0, 0, 0);
        oacc[1][nt] = __builtin_amdgcn_mfma_f32_16x16x32_bf16(paf[1], vf, oacc[1][nt], 0, 0, 0);
      }
    }
  }

  // ---- row-sum reduce across the 16 columns held in the quad's lanes ----
#pragma unroll
  for (int mt = 0; mt < 2; ++mt)
#pragma unroll
    for (int r = 0; r < 4; ++r) {
#pragma unroll
      for (int m = 1; m < 16; m <<= 1) lsum[mt][r] += __shfl_xor(lsum[mt][r], m);
    }

  // ---- split-K combine (wave1 -> LDS, wave0 adds + writes out) ----
  __syncthreads();
  if (w == 1) {
#pragma unroll
    for (int mt = 0; mt < 2; ++mt) {
#pragma unroll
      for (int nt = 0; nt < 12; ++nt)
#pragma unroll
        for (int r = 0; r < 4; ++r)
          smem[lane * 104 + (mt * 12 + nt) * 4 + r] = oacc[mt][nt][r];
#pragma unroll
      for (int r = 0; r < 4; ++r) smem[lane * 104 + 96 + mt * 4 + r] = lsum[mt][r];
    }
  }
  __syncthreads();
  if (w == 0) {
#pragma unroll
    for (int mt = 0; mt < 2; ++mt) {
      float linv[4];
#pragma unroll
      for (int r = 0; r < 4; ++r)
        linv[r] = 1.f / (lsum[mt][r] + smem[lane * 104 + 96 + mt * 4 + r]);
#pragma unroll
      for (int nt = 0; nt < 12; ++nt)
#pragma unroll
        for (int r = 0; r < 4; ++r) {
          float v = (oacc[mt][nt][r] + smem[lane * 104 + (mt * 12 + nt) * 4 + r]) * linv[r];
          out[((size_t)b * TT + q0 + mt * 16 + 4 * q + r) * CD + nt * 16 + L] = v;
        }
    }
  }
}

extern "C" void kernel_launch(void* const* d_in, const int* in_sizes, int n_in,
                              void* d_out, int out_size, void* d_ws, size_t ws_size,
                              hipStream_t stream) {
  (void)in_sizes; (void)n_in; (void)out_size; (void)ws_size;
  const float* qkv = (const float*)d_in[0];
  float* out = (float*)d_out;

  short8* qsw = (short8*)d_ws;                       // 8*256*6*64 units
  short8* ksw = qsw + (size_t)BB * 256 * 6 * 64;
  short8* vsw = ksw + (size_t)BB * 256 * 6 * 64;     // 8*12*128*64 units
  float* q2 = (float*)(vsw + (size_t)BB * 12 * 128 * 64);
  float* k2 = q2 + (size_t)BB * TT;

  // q2/k2 are atomically accumulated -> zero them (memsetAsync is capture-safe)
  hipMemsetAsync(q2, 0, (size_t)2 * BB * TT * sizeof(float), stream);

  swizzle_qk<<<BB * 256 * 6 * 2 / 4, 256, 0, stream>>>(qkv, qsw, ksw, q2, k2);
  swizzle_v<<<BB * 128, 256, 0, stream>>>(qkv, vsw);
  attn_main<<<BB * (TT / 32), 128, 0, stream>>>(qsw, ksw, vsw, q2, k2, out);
}

// Round 3
// 303.932 us; speedup vs baseline: 1.7447x; 1.6027x over previous
//
#include <hip/hip_runtime.h>
#include <hip/hip_bf16.h>

// QKVAttention: L2-distance attention. B=8, T=4096, C=192, fp32 in/out.
// out[b,t,:] = sum_s exp(-||q_t-k_s||*192^-0.5) v_s / sum_s exp(...)
// exp arg bounded in [-3,0] -> no online softmax needed.
//
// R3: R2 was L2-BW bound (each wave privately re-read K/V; 56 B/cyc/CU L2
// share vs 384KB/iter demand). Now: block = 4 waves x 32 q-rows = 128 rows,
// all waves share the SAME s-tile stream, K+V staged into LDS with
// global_load_lds (dwordx4) double-buffer, ST=32. L2 traffic 3.2GB -> 0.79GB.
// grid 256 = 8 batches (XCD-swizzled) x 32 q-blocks, 1 block/CU.
// P C->A layout fix via wave-private LDS scratch (16x36 fp32, reused per mt).

#define BB 8
#define TT 4096
#define CD 192

typedef __attribute__((ext_vector_type(8))) short short8;   // 8 bf16 (4 VGPR)
typedef __attribute__((ext_vector_type(4))) float float4v;  // MFMA C/D
typedef __attribute__((ext_vector_type(2))) unsigned int uint2v;

// (log2 e)^2 / 192  : p = exp2(-sqrt(A2C * max(d2_raw,0)))
constexpr float A2C = (float)(2.0813689810056077 / 192.0);

static __device__ __forceinline__ unsigned short f2bf(float f) {
  unsigned u = __builtin_bit_cast(unsigned, f);
  unsigned r = u + 0x7fffu + ((u >> 16) & 1u);   // RNE (inputs finite)
  return (unsigned short)(r >> 16);
}
static __device__ __forceinline__ float bf2f(unsigned short b) {
  return __builtin_bit_cast(float, (unsigned)b << 16);
}

// ---------------- fused prepass: qkv -> qsw/ksw/vsw fragments + q2/k2 -------
// block = (b, sc): 32 tokens x 576 ch. Coalesced float4 read -> bf16 LDS tile,
// then emit MFMA-fragment units (64 lanes x 16B each) + rounded row sumsq.
// No atomics: each block owns its 32 tokens' q2/k2 entries.
__global__ __launch_bounds__(256) void prep(
    const float* __restrict__ qkv, short8* __restrict__ qsw,
    short8* __restrict__ ksw, short8* __restrict__ vsw,
    float* __restrict__ q2, float* __restrict__ k2) {
  __shared__ unsigned short tile[32 * 584];   // row stride 584 (1168B, 16-mult)
  const int t = threadIdx.x;
  const int b = blockIdx.x >> 7;
  const int sc = blockIdx.x & 127;
  const float* src = qkv + ((size_t)(b * TT + sc * 32)) * (3 * CD);
#pragma unroll
  for (int j = 0; j < 18; ++j) {              // 4608 float4s / 256 thr
    int f = j * 256 + t;
    int row = f / 144, c4 = (f % 144) * 4;
    float4v x = *(const float4v*)(src + (size_t)row * 576 + c4);
    unsigned r0 = (unsigned)f2bf(x[0]) | ((unsigned)f2bf(x[1]) << 16);
    unsigned r1 = (unsigned)f2bf(x[2]) | ((unsigned)f2bf(x[3]) << 16);
    *(uint2v*)&tile[row * 584 + c4] = (uint2v){r0, r1};
  }
  __syncthreads();

  const int lane = t & 63, w = t >> 6;
  const int L = lane & 15, q = lane >> 4;
  // waves 0,1 -> q (s16o = w), waves 2,3 -> k (s16o = w-2)
  const int which = w >> 1;
  const int s16o = w & 1;
  const int row = s16o * 16 + L;
  short8* dst = which ? ksw : qsw;
  const size_t ubase = ((size_t)(b * 256 + sc * 2 + s16o)) * 6;
  float ss = 0.f;
#pragma unroll
  for (int ch = 0; ch < 6; ++ch) {
    short8 fr = *(const short8*)&tile[row * 584 + which * CD + ch * 32 + q * 8];
#pragma unroll
    for (int j = 0; j < 8; ++j) {
      float f = bf2f((unsigned short)fr[j]);
      ss += f * f;
    }
    dst[(ubase + ch) * 64 + lane] = fr;
  }
  ss += __shfl_xor(ss, 16);
  ss += __shfl_xor(ss, 32);                   // sum over 4 quads (192 ch)
  if (lane < 16)
    (which ? k2 : q2)[b * TT + sc * 32 + s16o * 16 + lane] = ss;

  // v fragments: 12 nt2-units, 3 per wave. lane(q,L): V[q*8+j][nt2*16+L]
#pragma unroll
  for (int i = 0; i < 3; ++i) {
    int nt2 = w * 3 + i;
    short8 fr;
#pragma unroll
    for (int j = 0; j < 8; ++j)
      fr[j] = (short)tile[(q * 8 + j) * 584 + 2 * CD + nt2 * 16 + L];
    vsw[((size_t)(b * 12 + nt2) * 128 + sc) * 64 + lane] = fr;
  }
}

// ---------------- main fused attention --------------------------------------
// block 256 = 4 waves; wave w: q-rows [qt*128 + w*32, +32) (mt=0,1 x 16).
// 128 s-iters of 32; K,V LDS double-buffered via global_load_lds width 16.
__global__ __launch_bounds__(256, 1) void attn2(
    const short8* __restrict__ qsw, const short8* __restrict__ ksw,
    const short8* __restrict__ vsw, const float* __restrict__ q2,
    const float* __restrict__ k2, float* __restrict__ out) {
  // LDS: K dbuf 2x12KB | V dbuf 2x12KB | P scratch 4 waves x 16x36 fp32
  __shared__ __align__(16) unsigned char s_lds[49152 + 9216];
  float* ldsP = (float*)(s_lds + 49152);

  const int tid = threadIdx.x;
  const int w = tid >> 6;
  const int lane = tid & 63;
  const int L = lane & 15;
  const int q = lane >> 4;
  const int b = blockIdx.x & 7;      // batch -> XCD
  const int qt = blockIdx.x >> 3;    // 0..31
  const int q0 = qt * 128 + w * 32;  // this wave's first q-row
  const size_t bT = (size_t)b * TT;

  float* pw = ldsP + w * 576;        // wave-private 16x36 P scratch

  // stage tile 'itile' (32 s-tokens) into buffer 'buf' (async, no wait)
  auto stage = [&](int itile, int buf) {
    const char* gk = (const char*)(ksw + ((size_t)(b * 256 + 2 * itile)) * 6 * 64);
#pragma unroll
    for (int j = 0; j < 3; ++j) {
      int u = w * 3 + j;
      const char* ga = gk + (u * 64 + lane) * 16;
      char* la = (char*)s_lds + buf * 12288 + u * 1024;
      __builtin_amdgcn_global_load_lds(
          (const __attribute__((address_space(1))) void*)ga,
          (__attribute__((address_space(3))) void*)la, 16, 0, 0);
    }
#pragma unroll
    for (int j = 0; j < 3; ++j) {
      int u = w * 3 + j;
      const char* ga = (const char*)vsw +
                       (((size_t)(b * 12 + u) * 128 + itile) * 64 + lane) * 16;
      char* la = (char*)s_lds + 24576 + buf * 12288 + u * 1024;
      __builtin_amdgcn_global_load_lds(
          (const __attribute__((address_space(1))) void*)ga,
          (__attribute__((address_space(3))) void*)la, 16, 0, 0);
    }
  };

  // Q fragments: unit ((b*256 + s16)*6 + ch), s16 = q0/16 + mt
  short8 qf[2][6];
#pragma unroll
  for (int mt = 0; mt < 2; ++mt)
#pragma unroll
    for (int ch = 0; ch < 6; ++ch)
      qf[mt][ch] = qsw[((size_t)(b * 256 + (q0 >> 4) + mt) * 6 + ch) * 64 + lane];

  float q2l[2][4];
#pragma unroll
  for (int mt = 0; mt < 2; ++mt)
#pragma unroll
    for (int r = 0; r < 4; ++r)
      q2l[mt][r] = q2[bT + q0 + mt * 16 + 4 * q + r];

  float4v oacc[2][12];
#pragma unroll
  for (int mt = 0; mt < 2; ++mt)
#pragma unroll
    for (int nt = 0; nt < 12; ++nt) oacc[mt][nt] = (float4v){0.f, 0.f, 0.f, 0.f};
  float lsum[2][4] = {{0.f, 0.f, 0.f, 0.f}, {0.f, 0.f, 0.f, 0.f}};

  stage(0, 0);
  __syncthreads();   // drains vmcnt -> tile0 ready

#pragma unroll 1
  for (int it = 0; it < 128; ++it) {
    const int cur = it & 1;
    if (it + 1 < 128) stage(it + 1, cur ^ 1);   // overlap with compute
    const int s0 = it * 32;

    float k2l[2];
    k2l[0] = k2[bT + s0 + L];
    k2l[1] = k2[bT + s0 + 16 + L];

    // ---- S = Q.K^T from LDS K fragments ----
    float4v sacc[2][2];
#pragma unroll
    for (int mt = 0; mt < 2; ++mt)
#pragma unroll
      for (int nt = 0; nt < 2; ++nt) sacc[mt][nt] = (float4v){0.f, 0.f, 0.f, 0.f};
#pragma unroll
    for (int ch = 0; ch < 6; ++ch) {
      short8 kf0 = *(const short8*)(s_lds + cur * 12288 + ch * 1024 + lane * 16);
      short8 kf1 = *(const short8*)(s_lds + cur * 12288 + (6 + ch) * 1024 + lane * 16);
      sacc[0][0] = __builtin_amdgcn_mfma_f32_16x16x32_bf16(qf[0][ch], kf0, sacc[0][0], 0, 0, 0);
      sacc[1][0] = __builtin_amdgcn_mfma_f32_16x16x32_bf16(qf[1][ch], kf0, sacc[1][0], 0, 0, 0);
      sacc[0][1] = __builtin_amdgcn_mfma_f32_16x16x32_bf16(qf[0][ch], kf1, sacc[0][1], 0, 0, 0);
      sacc[1][1] = __builtin_amdgcn_mfma_f32_16x16x32_bf16(qf[1][ch], kf1, sacc[1][1], 0, 0, 0);
    }

    // ---- V fragments from LDS (issue early; used after P) ----
    short8 vf[12];
#pragma unroll
    for (int nt = 0; nt < 12; ++nt)
      vf[nt] = *(const short8*)(s_lds + 24576 + cur * 12288 + nt * 1024 + lane * 16);

    // ---- P = exp(-dist) + C->A layout round trip (per mt, scratch reused) --
    short8 paf[2];
#pragma unroll
    for (int mt = 0; mt < 2; ++mt) {
#pragma unroll
      for (int nt = 0; nt < 2; ++nt)
#pragma unroll
        for (int r = 0; r < 4; ++r) {
          float dot = sacc[mt][nt][r];
          float tt = fmaf(-2.f, dot, q2l[mt][r] + k2l[nt]);   // raw d2
          float y = fmaxf(tt, 0.f) * A2C;
          float p = __builtin_amdgcn_exp2f(-__builtin_amdgcn_sqrtf(y));
          lsum[mt][r] += p;
          pw[(4 * q + r) * 36 + nt * 16 + L] = p;
        }
      float4v p0 = *(const float4v*)(pw + L * 36 + q * 8);
      float4v p1 = *(const float4v*)(pw + L * 36 + q * 8 + 4);
      short8 pa;
#pragma unroll
      for (int j = 0; j < 4; ++j) {
        pa[j] = (short)f2bf(p0[j]);
        pa[j + 4] = (short)f2bf(p1[j]);
      }
      paf[mt] = pa;
    }

    // ---- O += P.V ----
#pragma unroll
    for (int nt = 0; nt < 12; ++nt) {
      oacc[0][nt] = __builtin_amdgcn_mfma_f32_16x16x32_bf16(paf[0], vf[nt], oacc[0][nt], 0, 0, 0);
      oacc[1][nt] = __builtin_amdgcn_mfma_f32_16x16x32_bf16(paf[1], vf[nt], oacc[1][nt], 0, 0, 0);
    }

    __syncthreads();   // drain stage(it+1) + release buf[cur]
  }

  // ---- epilogue: normalize, write out (wave-private, no combine) ----
#pragma unroll
  for (int mt = 0; mt < 2; ++mt)
#pragma unroll
    for (int r = 0; r < 4; ++r) {
      float ls = lsum[mt][r];
#pragma unroll
      for (int m = 1; m < 16; m <<= 1) ls += __shfl_xor(ls, m);
      float linv = 1.f / ls;
#pragma unroll
      for (int nt = 0; nt < 12; ++nt)
        out[(bT + q0 + mt * 16 + 4 * q + r) * CD + nt * 16 + L] =
            oacc[mt][nt][r] * linv;
    }
}

extern "C" void kernel_launch(void* const* d_in, const int* in_sizes, int n_in,
                              void* d_out, int out_size, void* d_ws, size_t ws_size,
                              hipStream_t stream) {
  (void)in_sizes; (void)n_in; (void)out_size; (void)ws_size;
  const float* qkv = (const float*)d_in[0];
  float* out = (float*)d_out;

  short8* qsw = (short8*)d_ws;                       // 8*256*6 units
  short8* ksw = qsw + (size_t)BB * 256 * 6 * 64;
  short8* vsw = ksw + (size_t)BB * 256 * 6 * 64;     // 8*12*128 units
  float* q2 = (float*)(vsw + (size_t)BB * 12 * 128 * 64);
  float* k2 = q2 + (size_t)BB * TT;

  prep<<<BB * 128, 256, 0, stream>>>(qkv, qsw, ksw, vsw, q2, k2);
  attn2<<<BB * 32, 256, 0, stream>>>(qsw, ksw, vsw, q2, k2, out);
}

// Round 4
// 244.340 us; speedup vs baseline: 2.1703x; 1.2439x over previous
//
#include <hip/hip_runtime.h>
#include <hip/hip_bf16.h>

// QKVAttention: L2-distance attention. B=8, T=4096, C=192, fp32 in/out.
// out[b,t,:] = sum_s exp(-||q_t-k_s||*192^-0.5) v_s / sum_s exp(...)
// exp arg bounded in [-3,0] -> no online softmax needed.
//
// R4: R3 was latency-bound at 1 block/CU (grid 256 -> 1 wave/SIMD, occupancy
// 11.5%; 3956 cyc/CU-iter vs ~780 cyc of issue work). Now grid 512 =
// 8 b x 64 q-tiles of 64 rows (4 waves x 16 rows), 58KB LDS -> 2 blocks/CU =
// 2 waves/SIMD with INDEPENDENT barriers (block A's vmcnt/barrier drain
// overlaps block B's compute). q2/k2 pre-scaled by A2C (one less mul/score).

#define BB 8
#define TT 4096
#define CD 192

typedef __attribute__((ext_vector_type(8))) short short8;   // 8 bf16 (4 VGPR)
typedef __attribute__((ext_vector_type(4))) float float4v;  // MFMA C/D
typedef __attribute__((ext_vector_type(2))) unsigned int uint2v;

// (log2 e)^2 / 192  : p = exp2(-sqrt(max(q2A+k2A-2*A2C*dot, 0)))
constexpr float A2C = (float)(2.0813689810056077 / 192.0);

static __device__ __forceinline__ unsigned short f2bf(float f) {
  unsigned u = __builtin_bit_cast(unsigned, f);
  unsigned r = u + 0x7fffu + ((u >> 16) & 1u);   // RNE (inputs finite)
  return (unsigned short)(r >> 16);
}
static __device__ __forceinline__ float bf2f(unsigned short b) {
  return __builtin_bit_cast(float, (unsigned)b << 16);
}

// ---------------- fused prepass: qkv -> qsw/ksw/vsw fragments + q2/k2 -------
// block = (b, sc): 32 tokens x 576 ch. Coalesced float4 read -> bf16 LDS tile,
// then emit MFMA-fragment units (64 lanes x 16B each) + A2C-prescaled rounded
// row sumsq. No atomics: each block owns its 32 tokens' q2/k2 entries.
__global__ __launch_bounds__(256) void prep(
    const float* __restrict__ qkv, short8* __restrict__ qsw,
    short8* __restrict__ ksw, short8* __restrict__ vsw,
    float* __restrict__ q2, float* __restrict__ k2) {
  __shared__ unsigned short tile[32 * 584];   // row stride 584 (1168B, 16-mult)
  const int t = threadIdx.x;
  const int b = blockIdx.x >> 7;
  const int sc = blockIdx.x & 127;
  const float* src = qkv + ((size_t)(b * TT + sc * 32)) * (3 * CD);
#pragma unroll
  for (int j = 0; j < 18; ++j) {              // 4608 float4s / 256 thr
    int f = j * 256 + t;
    int row = f / 144, c4 = (f % 144) * 4;
    float4v x = *(const float4v*)(src + (size_t)row * 576 + c4);
    unsigned r0 = (unsigned)f2bf(x[0]) | ((unsigned)f2bf(x[1]) << 16);
    unsigned r1 = (unsigned)f2bf(x[2]) | ((unsigned)f2bf(x[3]) << 16);
    *(uint2v*)&tile[row * 584 + c4] = (uint2v){r0, r1};
  }
  __syncthreads();

  const int lane = t & 63, w = t >> 6;
  const int L = lane & 15, q = lane >> 4;
  // waves 0,1 -> q (s16o = w), waves 2,3 -> k (s16o = w-2)
  const int which = w >> 1;
  const int s16o = w & 1;
  const int row = s16o * 16 + L;
  short8* dst = which ? ksw : qsw;
  const size_t ubase = ((size_t)(b * 256 + sc * 2 + s16o)) * 6;
  float ss = 0.f;
#pragma unroll
  for (int ch = 0; ch < 6; ++ch) {
    short8 fr = *(const short8*)&tile[row * 584 + which * CD + ch * 32 + q * 8];
#pragma unroll
    for (int j = 0; j < 8; ++j) {
      float f = bf2f((unsigned short)fr[j]);
      ss += f * f;
    }
    dst[(ubase + ch) * 64 + lane] = fr;
  }
  ss += __shfl_xor(ss, 16);
  ss += __shfl_xor(ss, 32);                   // sum over 4 quads (192 ch)
  if (lane < 16)
    (which ? k2 : q2)[b * TT + sc * 32 + s16o * 16 + lane] = ss * A2C;

  // v fragments: 12 nt2-units, 3 per wave. lane(q,L): V[q*8+j][nt2*16+L]
#pragma unroll
  for (int i = 0; i < 3; ++i) {
    int nt2 = w * 3 + i;
    short8 fr;
#pragma unroll
    for (int j = 0; j < 8; ++j)
      fr[j] = (short)tile[(q * 8 + j) * 584 + 2 * CD + nt2 * 16 + L];
    vsw[((size_t)(b * 12 + nt2) * 128 + sc) * 64 + lane] = fr;
  }
}

// ---------------- main fused attention --------------------------------------
// grid 512 = 8 b x 64 q-tiles; block 256 = 4 waves x 16 q-rows.
// 128 s-iters of 32; K,V LDS double-buffered via global_load_lds width 16.
// 58368B LDS -> 2 blocks/CU (independent barriers overlap each other's drain).
__global__ __launch_bounds__(256, 2) void attn2(
    const short8* __restrict__ qsw, const short8* __restrict__ ksw,
    const short8* __restrict__ vsw, const float* __restrict__ q2,
    const float* __restrict__ k2, float* __restrict__ out) {
  // LDS: K dbuf 2x12KB | V dbuf 2x12KB | P scratch 4 waves x 16x36 fp32
  __shared__ __align__(16) unsigned char s_lds[49152 + 9216];
  float* ldsP = (float*)(s_lds + 49152);

  const int tid = threadIdx.x;
  const int w = tid >> 6;
  const int lane = tid & 63;
  const int L = lane & 15;
  const int q = lane >> 4;
  const int b = blockIdx.x & 7;      // batch -> XCD (and blk, blk+256 same CU
  const int qt = blockIdx.x >> 3;    //   share batch -> shared K/V in L2)
  const int q0 = qt * 64 + w * 16;   // this wave's 16 q-rows
  const size_t bT = (size_t)b * TT;

  float* pw = ldsP + w * 576;        // wave-private 16x36 P scratch

  // stage tile 'itile' (32 s-tokens: 12 K units + 12 V units) into buf
  auto stage = [&](int itile, int buf) {
    const char* gk = (const char*)(ksw + ((size_t)(b * 256 + 2 * itile)) * 6 * 64);
#pragma unroll
    for (int j = 0; j < 3; ++j) {
      int u = w * 3 + j;
      const char* ga = gk + (u * 64 + lane) * 16;
      char* la = (char*)s_lds + buf * 12288 + u * 1024;
      __builtin_amdgcn_global_load_lds(
          (const __attribute__((address_space(1))) void*)ga,
          (__attribute__((address_space(3))) void*)la, 16, 0, 0);
    }
#pragma unroll
    for (int j = 0; j < 3; ++j) {
      int u = w * 3 + j;
      const char* ga = (const char*)vsw +
                       (((size_t)(b * 12 + u) * 128 + itile) * 64 + lane) * 16;
      char* la = (char*)s_lds + 24576 + buf * 12288 + u * 1024;
      __builtin_amdgcn_global_load_lds(
          (const __attribute__((address_space(1))) void*)ga,
          (__attribute__((address_space(3))) void*)la, 16, 0, 0);
    }
  };

  // Q fragments: unit ((b*256 + s16)*6 + ch), s16 = q0/16 = qt*4 + w
  short8 qf[6];
#pragma unroll
  for (int ch = 0; ch < 6; ++ch)
    qf[ch] = qsw[((size_t)(b * 256 + (q0 >> 4)) * 6 + ch) * 64 + lane];

  float q2l[4];
#pragma unroll
  for (int r = 0; r < 4; ++r) q2l[r] = q2[bT + q0 + 4 * q + r];

  float4v oacc[12];
#pragma unroll
  for (int nt = 0; nt < 12; ++nt) oacc[nt] = (float4v){0.f, 0.f, 0.f, 0.f};
  float lsum[4] = {0.f, 0.f, 0.f, 0.f};

  stage(0, 0);
  __syncthreads();   // drains vmcnt -> tile0 ready

#pragma unroll 1
  for (int it = 0; it < 128; ++it) {
    const int cur = it & 1;
    if (it + 1 < 128) stage(it + 1, cur ^ 1);   // overlap with compute
    const int s0 = it * 32;

    float k2l[2];
    k2l[0] = k2[bT + s0 + L];
    k2l[1] = k2[bT + s0 + 16 + L];

    // ---- S = Q.K^T from LDS K fragments ----
    float4v sacc[2];
    sacc[0] = (float4v){0.f, 0.f, 0.f, 0.f};
    sacc[1] = (float4v){0.f, 0.f, 0.f, 0.f};
#pragma unroll
    for (int ch = 0; ch < 6; ++ch) {
      short8 kf0 = *(const short8*)(s_lds + cur * 12288 + ch * 1024 + lane * 16);
      short8 kf1 = *(const short8*)(s_lds + cur * 12288 + (6 + ch) * 1024 + lane * 16);
      sacc[0] = __builtin_amdgcn_mfma_f32_16x16x32_bf16(qf[ch], kf0, sacc[0], 0, 0, 0);
      sacc[1] = __builtin_amdgcn_mfma_f32_16x16x32_bf16(qf[ch], kf1, sacc[1], 0, 0, 0);
    }

    // ---- V fragments from LDS (issue early; used after P) ----
    short8 vf[12];
#pragma unroll
    for (int nt = 0; nt < 12; ++nt)
      vf[nt] = *(const short8*)(s_lds + 24576 + cur * 12288 + nt * 1024 + lane * 16);

    // ---- P = exp(-dist); C-layout row=4q+r, col=nt*16+L -> LDS -> A-layout --
#pragma unroll
    for (int nt = 0; nt < 2; ++nt)
#pragma unroll
      for (int r = 0; r < 4; ++r) {
        float dot = sacc[nt][r];
        float tt = fmaf(-2.f * A2C, dot, q2l[r] + k2l[nt]);   // scaled d2
        float y = fmaxf(tt, 0.f);
        float p = __builtin_amdgcn_exp2f(-__builtin_amdgcn_sqrtf(y));
        lsum[r] += p;
        pw[(4 * q + r) * 36 + nt * 16 + L] = p;
      }
    float4v p0 = *(const float4v*)(pw + L * 36 + q * 8);
    float4v p1 = *(const float4v*)(pw + L * 36 + q * 8 + 4);
    short8 paf;
#pragma unroll
    for (int j = 0; j < 4; ++j) {
      paf[j] = (short)f2bf(p0[j]);
      paf[j + 4] = (short)f2bf(p1[j]);
    }

    // ---- O += P.V ----
#pragma unroll
    for (int nt = 0; nt < 12; ++nt)
      oacc[nt] = __builtin_amdgcn_mfma_f32_16x16x32_bf16(paf, vf[nt], oacc[nt], 0, 0, 0);

    __syncthreads();   // drain stage(it+1) + release buf[cur]
  }

  // ---- epilogue: normalize, write out (wave-private) ----
#pragma unroll
  for (int r = 0; r < 4; ++r) {
    float ls = lsum[r];
#pragma unroll
    for (int m = 1; m < 16; m <<= 1) ls += __shfl_xor(ls, m);
    float linv = 1.f / ls;
#pragma unroll
    for (int nt = 0; nt < 12; ++nt)
      out[(bT + q0 + 4 * q + r) * CD + nt * 16 + L] = oacc[nt][r] * linv;
  }
}

extern "C" void kernel_launch(void* const* d_in, const int* in_sizes, int n_in,
                              void* d_out, int out_size, void* d_ws, size_t ws_size,
                              hipStream_t stream) {
  (void)in_sizes; (void)n_in; (void)out_size; (void)ws_size;
  const float* qkv = (const float*)d_in[0];
  float* out = (float*)d_out;

  short8* qsw = (short8*)d_ws;                       // 8*256*6 units
  short8* ksw = qsw + (size_t)BB * 256 * 6 * 64;
  short8* vsw = ksw + (size_t)BB * 256 * 6 * 64;     // 8*12*128 units
  float* q2 = (float*)(vsw + (size_t)BB * 12 * 128 * 64);
  float* k2 = q2 + (size_t)BB * TT;

  prep<<<BB * 128, 256, 0, stream>>>(qkv, qsw, ksw, vsw, q2, k2);
  attn2<<<BB * 64, 256, 0, stream>>>(qsw, ksw, vsw, q2, k2, out);
}